// Round 7
// baseline (10965.588 us; speedup 1.0000x reference)
//
#include <hip/hip_runtime.h>

// Problem constants
#define TT 256
#define DD 128
#define HH 256
#define PP 2048
#define RB 16     // rows per block
#define NBLK 128  // 2048/16
#define NTH 512   // 8 waves

typedef _Float16 half8 __attribute__((ext_vector_type(8)));
typedef _Float16 half4 __attribute__((ext_vector_type(4)));
typedef float f32x4 __attribute__((ext_vector_type(4)));

#define MFMA16(a, b, c) __builtin_amdgcn_mfma_f32_16x16x32_f16((a), (b), (c), 0, 0, 0)
#define INV2048 (4.8828125e-4f)

__device__ __forceinline__ float sigmoidf_(float v) { return 1.0f / (1.0f + expf(-v)); }

// Async global->LDS, 16B per lane. LDS dest is wave-uniform base + lane*16 (HW rule).
__device__ __forceinline__ void gload16(const void* g, void* l) {
    __builtin_amdgcn_global_load_lds((const __attribute__((address_space(1))) void*)g,
                                     (__attribute__((address_space(3))) void*)l, 16, 0, 0);
}

// ---------------------------------------------------------------------------
// Weight fragments (UNCHANGED from round 6 — verified absmax 0):
// sections sec = 2*s+part (s: 0..3 x-k, 4..11 h-k; part 0 hi, 1 lo*2048),
// each section = 48 tiles x 512 halves (1 KB per tile, lane-linear 16B).
__global__ void prep_kernel(const float* __restrict__ w_ih, const float* __restrict__ w_hh,
                            const float* __restrict__ protos,
                            _Float16* __restrict__ WF, float* __restrict__ pT) {
    int f = blockIdx.x * blockDim.x + threadIdx.x;
    if (f < 294912) {
        int s = f / 24576, rem = f % 24576;
        int tt = rem / 512, rem2 = rem % 512;
        int m = rem2 >> 5, kl = rem2 & 31;
        int grow = (tt % 3) * 256 + (tt / 3) * 16 + m;   // [r|z|n] within 16-unit chunk
        float v = (s < 4) ? w_ih[grow * DD + s * 32 + kl]
                          : w_hh[grow * HH + (s - 4) * 32 + kl];
        _Float16 hi = (_Float16)v;
        _Float16 lo = (_Float16)((v - (float)hi) * 2048.0f);
        int lane = m + 16 * (kl >> 3);
        int base = ((s * 2 + 0) * 48 + tt) * 512 + lane * 8 + (kl & 7);
        WF[base] = hi;
        WF[base + 48 * 512] = lo;   // part 1 section
    }
    if (f < HH * PP) pT[f] = protos[(f & (PP - 1)) * HH + (f >> 11)];
}

// ---------------------------------------------------------------------------
__launch_bounds__(NTH, 2)
__global__ void gru_kernel(const float* __restrict__ x,
                           const _Float16* __restrict__ WF,
                           const float* __restrict__ b_ih, const float* __restrict__ b_hh,
                           const float* __restrict__ pT,
                           int* __restrict__ out) {
    // LDS pool (152 KB): weight staging 96 KB | activation fragments 48 KB | x stage 8 KB
    __shared__ __align__(16) unsigned char smem[152 * 1024];
    unsigned char* const wst   = smem;                        // [8 waves][2 bufs][6 tiles][1024 B]
    _Float16* const fragB      = (_Float16*)(smem + 96 * 1024);  // [2][24 sec][512 halves]
    float* const xstage        = (float*)(smem + 144 * 1024);    // [16 rows][128 k] fp32
#define FRAG(b, sec) (fragB + ((b) * 24 + (sec)) * 512)

    const int tid  = threadIdx.x;
    const int lane = tid & 63;
    const int w    = tid >> 6;          // wave id: owns tiles 6w..6w+5 = units 32w..32w+31
    const int row0 = blockIdx.x * RB;
    const int lane8 = lane * 8;
    const int t0w   = w * 6;

    // Biases for this lane's 8 units: j = 32w + q*16 + (lane>>4)*4 + r
    float bRv[2][4], bZv[2][4], bXNv[2][4], bHNv[2][4];
    #pragma unroll
    for (int q = 0; q < 2; ++q)
        #pragma unroll
        for (int r = 0; r < 4; ++r) {
            const int j = 32 * w + q * 16 + ((lane >> 4) << 2) + r;
            bRv[q][r]  = b_ih[j] + b_hh[j];
            bZv[q][r]  = b_ih[HH + j] + b_hh[HH + j];
            bXNv[q][r] = b_ih[2 * HH + j];
            bHNv[q][r] = b_hh[2 * HH + j];
        }

    float hprev[2][4];
    #pragma unroll
    for (int q = 0; q < 2; ++q)
        #pragma unroll
        for (int r = 0; r < 4; ++r) hprev[q][r] = 0.0f;

    // x staging: wave w loads rows 2w,2w+1 (one gload16: lane<32 -> row 2w, lane>=32 -> row 2w+1)
    const int xr = 2 * w + (lane >> 5);
    const int xc = (lane & 31) * 4;
    const float* const xsrc = x + (size_t)(row0 + xr) * TT * DD + xc;
    float* const xdst = xstage + 2 * w * DD;   // wave-uniform dest base
    // x fragment conversion mapping (thread-level, wave-local rows)
    const int xn = tid >> 5, xk0 = (tid & 31) * 4;
    const int xsec = 2 * (xk0 >> 5);
    const int xidx = (((xk0 & 31) >> 3) * 16 + xn) * 8 + (xk0 & 7);

    // ---- prime: stage + convert x_0, zero h fragments of buf 0 ----
    gload16(xsrc, xdst);
    asm volatile("s_waitcnt vmcnt(0)" ::: "memory");
    {
        const float4 v = *(const float4*)&xstage[xn * DD + xk0];
        const float vv[4] = {v.x, v.y, v.z, v.w};
        _Float16 xh[4], xl[4];
        #pragma unroll
        for (int u = 0; u < 4; ++u) {
            xh[u] = (_Float16)vv[u];
            xl[u] = (_Float16)((vv[u] - (float)xh[u]) * 2048.0f);
        }
        *(half4*)(FRAG(0, xsec) + xidx)     = half4{xh[0], xh[1], xh[2], xh[3]};
        *(half4*)(FRAG(0, xsec + 1) + xidx) = half4{xl[0], xl[1], xl[2], xl[3]};
        _Float16* hz = FRAG(0, 8);
        const half8 z8 = {};
        *(half8*)(hz + tid * 16)     = z8;
        *(half8*)(hz + tid * 16 + 8) = z8;
    }
    __syncthreads();

    const char* const WFb = (const char*)WF;
    unsigned char* const wb0 = wst + (size_t)(w * 2 + 0) * 6144;
    unsigned char* const wb1 = wst + (size_t)(w * 2 + 1) * 6144;

    // Stage section `sec`'s 6 tiles of this wave into buffer wb (6 x 1KB async loads)
#define ISSUE_SEC(sec, wb) do {                                                \
        const char* _sb = WFb + (size_t)((sec) * 48 + t0w) * 1024 + lane * 16; \
        _Pragma("unroll")                                                      \
        for (int _i = 0; _i < 6; ++_i)                                         \
            gload16(_sb + _i * 1024, (wb) + _i * 1024);                        \
    } while (0)

    for (int t = 0; t < TT; ++t) {
        const int cur = t & 1, nxtb = cur ^ 1;

        // issue pipeline head: S(0), S(1), then x_{t+1} (dummy slice 0 at last step
        // to keep the vmcnt ledger uniform)
        ISSUE_SEC(0, wb0);
        ISSUE_SEC(1, wb1);
        const int t1 = (t + 1 < TT) ? (t + 1) : 0;
        gload16(xsrc + (size_t)t1 * DD, xdst);

        f32x4 a1m[6], a1x[6], a2m[6], a2x[6];
        #pragma unroll
        for (int i = 0; i < 6; ++i) {
            a1m[i] = f32x4{0.f, 0.f, 0.f, 0.f}; a1x[i] = f32x4{0.f, 0.f, 0.f, 0.f};
            a2m[i] = f32x4{0.f, 0.f, 0.f, 0.f}; a2x[i] = f32x4{0.f, 0.f, 0.f, 0.f};
        }

        // ---- 24 phases (sections), wave-private staging, no barriers ----
        // vmcnt ledger (in-order retirement): issue order S0,S1,X,S2,S3,...
        // p=0,1: wait 7 (leaves S(p+1)+X) ; p=2..22: wait 6 ; p=23: wait 0.
        half8 bh, bl;
        #pragma unroll
        for (int p = 0; p < 24; ++p) {
            if (p < 2)       asm volatile("s_waitcnt vmcnt(7)" ::: "memory");
            else if (p < 23) asm volatile("s_waitcnt vmcnt(6)" ::: "memory");
            else             asm volatile("s_waitcnt vmcnt(0)" ::: "memory");
            unsigned char* const wb = (p & 1) ? wb1 : wb0;
            const int s = p >> 1;
            if ((p & 1) == 0) {
                bh = *(const half8*)(FRAG(cur, 2 * s) + lane8);
                bl = *(const half8*)(FRAG(cur, 2 * s + 1) + lane8);
                #pragma unroll
                for (int i = 0; i < 6; ++i) {
                    const half8 wv = *(const half8*)(wb + i * 1024 + lane * 16);
                    if (s < 4) { a1m[i] = MFMA16(wv, bh, a1m[i]); a1x[i] = MFMA16(wv, bl, a1x[i]); }
                    else       { a2m[i] = MFMA16(wv, bh, a2m[i]); a2x[i] = MFMA16(wv, bl, a2x[i]); }
                }
            } else {
                #pragma unroll
                for (int i = 0; i < 6; ++i) {
                    const half8 wv = *(const half8*)(wb + i * 1024 + lane * 16);
                    if (s < 4) a1x[i] = MFMA16(wv, bh, a1x[i]);
                    else       a2x[i] = MFMA16(wv, bh, a2x[i]);
                }
            }
            __builtin_amdgcn_sched_barrier(0);   // pin: consume before re-staging this buffer
            if (p <= 21) ISSUE_SEC(p + 2, wb);
        }

        // ---- stage x_{t+1} fragments (X retired at p=2's wait at the latest) ----
        if (t + 1 < TT) {
            const float4 v = *(const float4*)&xstage[xn * DD + xk0];
            const float vv[4] = {v.x, v.y, v.z, v.w};
            _Float16 xh[4], xl[4];
            #pragma unroll
            for (int u = 0; u < 4; ++u) {
                xh[u] = (_Float16)vv[u];
                xl[u] = (_Float16)((vv[u] - (float)xh[u]) * 2048.0f);
            }
            *(half4*)(FRAG(nxtb, xsec) + xidx)     = half4{xh[0], xh[1], xh[2], xh[3]};
            *(half4*)(FRAG(nxtb, xsec + 1) + xidx) = half4{xl[0], xl[1], xl[2], xl[3]};
        }

        // ---- gates + h update (round-6 verified math) ----
        #pragma unroll
        for (int q = 0; q < 2; ++q) {
            _Float16 hh_[4], hl_[4];
            #pragma unroll
            for (int r = 0; r < 4; ++r) {
                const float c1r = a1m[q * 3 + 0][r] + a1x[q * 3 + 0][r] * INV2048;
                const float c2r = a2m[q * 3 + 0][r] + a2x[q * 3 + 0][r] * INV2048;
                const float c1z = a1m[q * 3 + 1][r] + a1x[q * 3 + 1][r] * INV2048;
                const float c2z = a2m[q * 3 + 1][r] + a2x[q * 3 + 1][r] * INV2048;
                const float c1n = a1m[q * 3 + 2][r] + a1x[q * 3 + 2][r] * INV2048;
                const float c2n = a2m[q * 3 + 2][r] + a2x[q * 3 + 2][r] * INV2048;
                const float Rg = sigmoidf_(c1r + c2r + bRv[q][r]);
                const float Zg = sigmoidf_(c1z + c2z + bZv[q][r]);
                const float Ng = tanhf(c1n + bXNv[q][r] + Rg * (c2n + bHNv[q][r]));
                const float h = (1.0f - Zg) * Ng + Zg * hprev[q][r];
                hprev[q][r] = h;
                hh_[r] = (_Float16)h;
                hl_[r] = (_Float16)((h - (float)hh_[r]) * 2048.0f);
            }
            const int jb  = 32 * w + q * 16 + ((lane >> 4) << 2);
            const int sec = 2 * (4 + (jb >> 5));
            const int idx = (((jb & 31) >> 3) * 16 + (lane & 15)) * 8 + (jb & 7);
            *(half4*)(FRAG(nxtb, sec) + idx)     = half4{hh_[0], hh_[1], hh_[2], hh_[3]};
            *(half4*)(FRAG(nxtb, sec + 1) + idx) = half4{hl_[0], hl_[1], hl_[2], hl_[3]};
        }
        __syncthreads();   // frag[nxtb] visible to all waves; wave staging is private
    }

    // ---- final h -> LDS fp32 (alias the weight-staging region) ----
    float* const hsF = (float*)smem;                       // [HH][RB]
    float (*redv)[RB] = (float (*)[RB])(smem + 16 * 1024); // [8][16]
    int   (*redi)[RB] = (int (*)[RB])(smem + 17 * 1024);
    #pragma unroll
    for (int q = 0; q < 2; ++q)
        #pragma unroll
        for (int r = 0; r < 4; ++r) {
            const int j = 32 * w + q * 16 + ((lane >> 4) << 2) + r;
            hsF[j * RB + (lane & 15)] = hprev[q][r];
        }
    __syncthreads();

    // ---- cdist^2 + argmin over P=2048: thread covers protos {tid, +512, +1024, +1536} ----
    float bv[16]; int bi[16];
    #pragma unroll
    for (int r = 0; r < 16; ++r) { bv[r] = 3.4e38f; bi[r] = 0; }
    for (int m = 0; m < 4; ++m) {
        const int p = m * 512 + tid;
        float d2[16];
        #pragma unroll
        for (int r = 0; r < 16; ++r) d2[r] = 0.f;
        #pragma unroll 2
        for (int k = 0; k < HH; ++k) {
            const float pv = pT[(size_t)k * PP + p];
            #pragma unroll
            for (int g4 = 0; g4 < 4; ++g4) {
                const float4 hv = *(const float4*)&hsF[k * RB + g4 * 4];
                float d;
                d = hv.x - pv; d2[g4 * 4 + 0] += d * d;
                d = hv.y - pv; d2[g4 * 4 + 1] += d * d;
                d = hv.z - pv; d2[g4 * 4 + 2] += d * d;
                d = hv.w - pv; d2[g4 * 4 + 3] += d * d;
            }
        }
        #pragma unroll
        for (int r = 0; r < 16; ++r)
            if (d2[r] < bv[r]) { bv[r] = d2[r]; bi[r] = p; }  // ascending p: keeps lowest on tie
    }
    #pragma unroll
    for (int s = 1; s < 64; s <<= 1) {
        #pragma unroll
        for (int r = 0; r < 16; ++r) {
            const float ov = __shfl_xor(bv[r], s);
            const int   oi = __shfl_xor(bi[r], s);
            if (ov < bv[r] || (ov == bv[r] && oi < bi[r])) { bv[r] = ov; bi[r] = oi; }
        }
    }
    if (lane == 0) {
        #pragma unroll
        for (int r = 0; r < 16; ++r) { redv[w][r] = bv[r]; redi[w][r] = bi[r]; }
    }
    __syncthreads();
    if (tid < RB) {
        float v = redv[0][tid]; int idx = redi[0][tid];
        #pragma unroll
        for (int u = 1; u < 8; ++u) {
            const float ov = redv[u][tid]; const int oi = redi[u][tid];
            if (ov < v || (ov == v && oi < idx)) { v = ov; idx = oi; }
        }
        out[row0 + tid] = idx;
    }
}

extern "C" void kernel_launch(void* const* d_in, const int* in_sizes, int n_in,
                              void* d_out, int out_size, void* d_ws, size_t ws_size,
                              hipStream_t stream) {
    const float* x      = (const float*)d_in[0];
    const float* w_ih   = (const float*)d_in[1];
    const float* w_hh   = (const float*)d_in[2];
    const float* b_ih   = (const float*)d_in[3];
    const float* b_hh   = (const float*)d_in[4];
    const float* protos = (const float*)d_in[5];
    int* out = (int*)d_out;

    _Float16* WF = (_Float16*)d_ws;                 // 589824 halves = 1.125 MB
    float*    pT = (float*)((char*)d_ws + 589824 * sizeof(_Float16));  // 2 MB

    hipLaunchKernelGGL(prep_kernel, dim3((HH * PP + 255) / 256), dim3(256), 0, stream,
                       w_ih, w_hh, protos, WF, pT);
    hipLaunchKernelGGL(gru_kernel, dim3(NBLK), dim3(NTH), 0, stream,
                       x, WF, b_ih, b_hh, pT, out);
}

// Round 8
// 3795.861 us; speedup vs baseline: 2.8888x; 2.8888x over previous
//
#include <hip/hip_runtime.h>

// Problem constants
#define TT 256
#define DD 128
#define HH 256
#define PP 2048
#define RB 16     // rows per block
#define NBLK 128  // 2048/16
#define NTH 768   // 12 waves, 3 per SIMD

typedef _Float16 half8 __attribute__((ext_vector_type(8)));
typedef _Float16 half4 __attribute__((ext_vector_type(4)));
typedef float f32x4 __attribute__((ext_vector_type(4)));

#define MFMA16(a, b, c) __builtin_amdgcn_mfma_f32_16x16x32_f16((a), (b), (c), 0, 0, 0)
#define INV2048 (4.8828125e-4f)

__device__ __forceinline__ float sigmoidf_(float v) { return 1.0f / (1.0f + expf(-v)); }

// ---------------------------------------------------------------------------
// Weight fragments (UNCHANGED layout from rounds 6/7 — verified absmax 0):
// sections sec = 2*s+part (s: 0..3 x-k, 4..11 h-k; part 0 hi, 1 lo*2048),
// each section = 48 tiles x 512 halves. Tile tt = chunk*3 + gate covers
// gate-type (tt%3) of units (tt/3)*16..+15; element (m,k): half
// (m + 16*(k>>3))*8 + (k&7).
__global__ void prep_kernel(const float* __restrict__ w_ih, const float* __restrict__ w_hh,
                            const float* __restrict__ protos,
                            _Float16* __restrict__ WF, float* __restrict__ pT) {
    int f = blockIdx.x * blockDim.x + threadIdx.x;
    if (f < 294912) {
        int s = f / 24576, rem = f % 24576;
        int tt = rem / 512, rem2 = rem % 512;
        int m = rem2 >> 5, kl = rem2 & 31;
        int grow = (tt % 3) * 256 + (tt / 3) * 16 + m;
        float v = (s < 4) ? w_ih[grow * DD + s * 32 + kl]
                          : w_hh[grow * HH + (s - 4) * 32 + kl];
        _Float16 hi = (_Float16)v;
        _Float16 lo = (_Float16)((v - (float)hi) * 2048.0f);
        int lane = m + 16 * (kl >> 3);
        int base = ((s * 2 + 0) * 48 + tt) * 512 + lane * 8 + (kl & 7);
        WF[base] = hi;
        WF[base + 48 * 512] = lo;
    }
    if (f < HH * PP) pT[f] = protos[(f & (PP - 1)) * HH + (f >> 11)];
}

// ---------------------------------------------------------------------------
__launch_bounds__(NTH, 1)
__global__ void gru_kernel(const float* __restrict__ x,
                           const _Float16* __restrict__ WF,
                           const float* __restrict__ b_ih, const float* __restrict__ b_hh,
                           const float* __restrict__ pT,
                           int* __restrict__ out) {
    __shared__ __align__(16) _Float16 frag[24][512];   // 24 KB activation fragments
    __shared__ __align__(16) float gates[64 * 256];    // 64 KB gate exchange (+hn planes 48..63)
    __shared__ float redv[12][RB];
    __shared__ int   redi[12][RB];

    const int tid  = threadIdx.x;
    const int lane = tid & 63;
    const int w    = tid >> 6;       // wave 0..11: owns gate-tiles 4w..4w+3
    const int row0 = blockIdx.x * RB;
    const int lane8 = lane * 8;
    const int tt0   = 4 * w;

    // ---- h-update ownership (tid<512): unit j, rows rh*8..rh*8+7 ----
    const int j  = tid & 255;
    const int rh = (tid >> 8) & 1;
    float bR = 0.f, bZ = 0.f, bXN = 0.f, bHN = 0.f;
    if (tid < 512) {
        bR  = b_ih[j] + b_hh[j];
        bZ  = b_ih[HH + j] + b_hh[HH + j];
        bXN = b_ih[2 * HH + j];
        bHN = b_hh[2 * HH + j];
    }
    float hprev[8];
    #pragma unroll
    for (int r = 0; r < 8; ++r) hprev[r] = 0.0f;
    const int hsec  = 2 * (4 + (j >> 5));
    const int hbase = ((j & 31) >> 3) * 128 + (j & 7);   // + row*8

    // ---- x loader mapping (tid<512): row xr, 4 consecutive k at xk0 ----
    const int xr  = (tid >> 5) & 15;
    const int xk0 = (tid & 31) * 4;
    const float* const xrow = x + (size_t)(row0 + xr) * TT * DD + xk0;
    const int xsec = 2 * (xk0 >> 5);
    const int xidx = (((xk0 & 31) >> 3) * 16 + xr) * 8 + (xk0 & 7);

    // ---- prime: x_0 fragments + zero h fragments ----
    if (tid < 512) {
        const float4 v = *(const float4*)xrow;
        const float vv[4] = {v.x, v.y, v.z, v.w};
        _Float16 xh[4], xl[4];
        #pragma unroll
        for (int u = 0; u < 4; ++u) {
            xh[u] = (_Float16)vv[u];
            xl[u] = (_Float16)((vv[u] - (float)xh[u]) * 2048.0f);
        }
        *(half4*)&frag[xsec][xidx]     = half4{xh[0], xh[1], xh[2], xh[3]};
        *(half4*)&frag[xsec + 1][xidx] = half4{xl[0], xl[1], xl[2], xl[3]};
        _Float16* hz = &frag[8][0];
        const half8 z8 = {};
        *(half8*)(hz + tid * 16)     = z8;
        *(half8*)(hz + tid * 16 + 8) = z8;
    }
    __syncthreads();

    const half8* __restrict__ WH = (const half8*)WF;

    for (int t = 0; t < TT; ++t) {
        // prefetch next x into regs (consumed after barrier A)
        float4 pfx = make_float4(0.f, 0.f, 0.f, 0.f);
        if ((t + 1 < TT) && tid < 512) pfx = *(const float4*)(xrow + (size_t)(t + 1) * DD);

        f32x4 aMx[4], aXx[4], aMh[4], aXh[4];
        #pragma unroll
        for (int i = 0; i < 4; ++i) {
            aMx[i] = f32x4{0.f, 0.f, 0.f, 0.f}; aXx[i] = f32x4{0.f, 0.f, 0.f, 0.f};
            aMh[i] = f32x4{0.f, 0.f, 0.f, 0.f}; aXh[i] = f32x4{0.f, 0.f, 0.f, 0.f};
        }

        // ---- x-GEMM (k-steps 0..3): plain loads, compiler-pipelined ----
        #pragma unroll 2
        for (int s = 0; s < 4; ++s) {
            const half8 bh = *(const half8*)&frag[2 * s][lane8];
            const half8 bl = *(const half8*)&frag[2 * s + 1][lane8];
            #pragma unroll
            for (int i = 0; i < 4; ++i) {
                const half8 wh = WH[((2 * s) * 48 + tt0 + i) * 64 + lane];
                const half8 wl = WH[((2 * s + 1) * 48 + tt0 + i) * 64 + lane];
                aMx[i] = MFMA16(wh, bh, aMx[i]);
                aXx[i] = MFMA16(wh, bl, aXx[i]);
                aXx[i] = MFMA16(wl, bh, aXx[i]);
            }
        }
        // ---- h-GEMM (k-steps 4..11) ----
        #pragma unroll 2
        for (int s = 4; s < 12; ++s) {
            const half8 bh = *(const half8*)&frag[2 * s][lane8];
            const half8 bl = *(const half8*)&frag[2 * s + 1][lane8];
            #pragma unroll
            for (int i = 0; i < 4; ++i) {
                const half8 wh = WH[((2 * s) * 48 + tt0 + i) * 64 + lane];
                const half8 wl = WH[((2 * s + 1) * 48 + tt0 + i) * 64 + lane];
                aMh[i] = MFMA16(wh, bh, aMh[i]);
                aXh[i] = MFMA16(wh, bl, aXh[i]);
                aXh[i] = MFMA16(wl, bh, aXh[i]);
            }
        }

        // ---- fold hi/lo and publish gate pre-activations ----
        // C-layout: col = lane&15 = batch row; m = (lane>>4)*4+q = gate-within-tile.
        {
            const int m0 = (lane >> 4) * 4, col = lane & 15;
            #pragma unroll
            for (int i = 0; i < 4; ++i) {
                const int tt = tt0 + i;
                if (tt % 3 == 2) {   // n-tile: keep x-part and h-part separate
                    const int cc = tt / 3;
                    #pragma unroll
                    for (int q = 0; q < 4; ++q) {
                        gates[tt * 256 + (m0 + q) * 16 + col] = aMx[i][q] + aXx[i][q] * INV2048;
                        gates[(48 + cc) * 256 + (m0 + q) * 16 + col] = aMh[i][q] + aXh[i][q] * INV2048;
                    }
                } else {
                    #pragma unroll
                    for (int q = 0; q < 4; ++q)
                        gates[tt * 256 + (m0 + q) * 16 + col] =
                            (aMx[i][q] + aMh[i][q]) + (aXx[i][q] + aXh[i][q]) * INV2048;
                }
            }
        }
        __syncthreads();   // A: gates visible; frag reads done

        // ---- gates -> h update (thread-local), write h & x fragments for t+1 ----
        if (tid < 512) {
            const int cc = j >> 4, jm = j & 15;
            const float* gr_ = &gates[(cc * 3 + 0) * 256 + jm * 16 + rh * 8];
            const float* gz_ = &gates[(cc * 3 + 1) * 256 + jm * 16 + rh * 8];
            const float* gx_ = &gates[(cc * 3 + 2) * 256 + jm * 16 + rh * 8];
            const float* gh_ = &gates[(48 + cc) * 256 + jm * 16 + rh * 8];
            #pragma unroll
            for (int r = 0; r < 8; ++r) {
                const float Rg = sigmoidf_(gr_[r] + bR);
                const float Zg = sigmoidf_(gz_[r] + bZ);
                const float Ng = tanhf(gx_[r] + bXN + Rg * (gh_[r] + bHN));
                const float h = (1.0f - Zg) * Ng + Zg * hprev[r];
                hprev[r] = h;
                const _Float16 hh = (_Float16)h;
                const _Float16 hl = (_Float16)((h - (float)hh) * 2048.0f);
                const int idx = hbase + (rh * 8 + r) * 8;
                frag[hsec][idx]     = hh;
                frag[hsec + 1][idx] = hl;
            }
            if (t + 1 < TT) {
                const float vv[4] = {pfx.x, pfx.y, pfx.z, pfx.w};
                _Float16 xh[4], xl[4];
                #pragma unroll
                for (int u = 0; u < 4; ++u) {
                    xh[u] = (_Float16)vv[u];
                    xl[u] = (_Float16)((vv[u] - (float)xh[u]) * 2048.0f);
                }
                *(half4*)&frag[xsec][xidx]     = half4{xh[0], xh[1], xh[2], xh[3]};
                *(half4*)&frag[xsec + 1][xidx] = half4{xl[0], xl[1], xl[2], xl[3]};
            }
        }
        __syncthreads();   // B: frag ready for next step; gates free
    }

    // ---- final h -> LDS fp32 (reuse gates region: hsF[j][row] = gates[j*16+row]) ----
    if (tid < 512) {
        #pragma unroll
        for (int r = 0; r < 8; ++r) gates[j * 16 + rh * 8 + r] = hprev[r];
    }
    __syncthreads();

    // ---- cdist^2 + argmin: thread covers protos {tid, tid+768, tid+1536} ----
    float bv[16]; int bi[16];
    #pragma unroll
    for (int r = 0; r < 16; ++r) { bv[r] = 3.4e38f; bi[r] = 0; }
    for (int m = 0; m < 3; ++m) {
        const int p = tid + m * 768;
        if (p < PP) {
            float d2[16];
            #pragma unroll
            for (int r = 0; r < 16; ++r) d2[r] = 0.f;
            #pragma unroll 2
            for (int k = 0; k < HH; ++k) {
                const float pv = pT[(size_t)k * PP + p];
                #pragma unroll
                for (int g4 = 0; g4 < 4; ++g4) {
                    const float4 hv = *(const float4*)&gates[k * 16 + g4 * 4];
                    float d;
                    d = hv.x - pv; d2[g4 * 4 + 0] += d * d;
                    d = hv.y - pv; d2[g4 * 4 + 1] += d * d;
                    d = hv.z - pv; d2[g4 * 4 + 2] += d * d;
                    d = hv.w - pv; d2[g4 * 4 + 3] += d * d;
                }
            }
            #pragma unroll
            for (int r = 0; r < 16; ++r)
                if (d2[r] < bv[r]) { bv[r] = d2[r]; bi[r] = p; }  // ascending p: lowest on tie
        }
    }
    #pragma unroll
    for (int s = 1; s < 64; s <<= 1) {
        #pragma unroll
        for (int r = 0; r < 16; ++r) {
            const float ov = __shfl_xor(bv[r], s);
            const int   oi = __shfl_xor(bi[r], s);
            if (ov < bv[r] || (ov == bv[r] && oi < bi[r])) { bv[r] = ov; bi[r] = oi; }
        }
    }
    if (lane == 0) {
        #pragma unroll
        for (int r = 0; r < 16; ++r) { redv[w][r] = bv[r]; redi[w][r] = bi[r]; }
    }
    __syncthreads();
    if (tid < RB) {
        float v = redv[0][tid]; int idx = redi[0][tid];
        #pragma unroll
        for (int u = 1; u < 12; ++u) {
            const float ov = redv[u][tid]; const int oi = redi[u][tid];
            if (ov < v || (ov == v && oi < idx)) { v = ov; idx = oi; }
        }
        out[row0 + tid] = idx;
    }
}

extern "C" void kernel_launch(void* const* d_in, const int* in_sizes, int n_in,
                              void* d_out, int out_size, void* d_ws, size_t ws_size,
                              hipStream_t stream) {
    const float* x      = (const float*)d_in[0];
    const float* w_ih   = (const float*)d_in[1];
    const float* w_hh   = (const float*)d_in[2];
    const float* b_ih   = (const float*)d_in[3];
    const float* b_hh   = (const float*)d_in[4];
    const float* protos = (const float*)d_in[5];
    int* out = (int*)d_out;

    _Float16* WF = (_Float16*)d_ws;                                   // 1.125 MB
    float*    pT = (float*)((char*)d_ws + 589824 * sizeof(_Float16)); // 2 MB

    hipLaunchKernelGGL(prep_kernel, dim3((HH * PP + 255) / 256), dim3(256), 0, stream,
                       w_ih, w_hh, protos, WF, pT);
    hipLaunchKernelGGL(gru_kernel, dim3(NBLK), dim3(NTH), 0, stream,
                       x, WF, b_ih, b_hh, pT, out);
}

// Round 9
// 3735.135 us; speedup vs baseline: 2.9358x; 1.0163x over previous
//
#include <hip/hip_runtime.h>

// Problem constants
#define TT 256
#define DD 128
#define HH 256
#define PP 2048
#define RB 16     // rows per block
#define NBLK 128  // 2048/16
#define NTH 512   // 8 waves, 2 per SIMD

typedef _Float16 half8 __attribute__((ext_vector_type(8)));
typedef _Float16 half4 __attribute__((ext_vector_type(4)));
typedef float f32x4 __attribute__((ext_vector_type(4)));

#define MFMA16(a, b, c) __builtin_amdgcn_mfma_f32_16x16x32_f16((a), (b), (c), 0, 0, 0)
#define INV2048 (4.8828125e-4f)

__device__ __forceinline__ float sigmoidf_(float v) { return 1.0f / (1.0f + expf(-v)); }

// ---------------------------------------------------------------------------
// Weight fragments (UNCHANGED layout from rounds 6-8 — verified absmax 0):
// sections sec = 2*s+part (s: 0..3 x-k, 4..11 h-k; part 0 hi, 1 lo*2048),
// each section = 48 tiles x 512 halves. Tile tt = chunk*3 + gate covers
// gate-type (tt%3) of units (tt/3)*16..+15; element (m,k): half
// (m + 16*(k>>3))*8 + (k&7).
__global__ void prep_kernel(const float* __restrict__ w_ih, const float* __restrict__ w_hh,
                            const float* __restrict__ protos,
                            _Float16* __restrict__ WF, float* __restrict__ pT) {
    int f = blockIdx.x * blockDim.x + threadIdx.x;
    if (f < 294912) {
        int s = f / 24576, rem = f % 24576;
        int tt = rem / 512, rem2 = rem % 512;
        int m = rem2 >> 5, kl = rem2 & 31;
        int grow = (tt % 3) * 256 + (tt / 3) * 16 + m;
        float v = (s < 4) ? w_ih[grow * DD + s * 32 + kl]
                          : w_hh[grow * HH + (s - 4) * 32 + kl];
        _Float16 hi = (_Float16)v;
        _Float16 lo = (_Float16)((v - (float)hi) * 2048.0f);
        int lane = m + 16 * (kl >> 3);
        int base = ((s * 2 + 0) * 48 + tt) * 512 + lane * 8 + (kl & 7);
        WF[base] = hi;
        WF[base + 48 * 512] = lo;
    }
    if (f < HH * PP) pT[f] = protos[(f & (PP - 1)) * HH + (f >> 11)];
}

// ---------------------------------------------------------------------------
// 8 waves; wave w owns tiles 6w..6w+5 = chunks 2w,2w+1 x gates {r,z,n}.
// Lane's C-fragments of the 3 gate-tiles of a chunk refer to the SAME
// (4 units, 1 row) -> gates computed fully in-register, 1 barrier/step.
__launch_bounds__(NTH, 2)
__global__ void gru_kernel(const float* __restrict__ x,
                           const _Float16* __restrict__ WF,
                           const float* __restrict__ b_ih, const float* __restrict__ b_hh,
                           const float* __restrict__ pT,
                           int* __restrict__ out) {
    // 84 KB LDS pool -> guarantees 1 block/CU (2 blocks would double the weight stream)
    __shared__ __align__(16) unsigned char smem[86016];
    _Float16* const fragB = (_Float16*)smem;              // [2][24 sec][512 halves] = 48 KB
    float* const hsF      = (float*)(smem + 49152);       // [256][16] = 16 KB (post-loop)
    float (*redv)[RB]     = (float (*)[RB])(smem + 65536);
    int   (*redi)[RB]     = (int   (*)[RB])(smem + 66048);
#define FRAG(b, sec) (fragB + ((b) * 24 + (sec)) * 512)

    const int tid  = threadIdx.x;
    const int lane = tid & 63;
    const int w    = tid >> 6;          // 0..7
    const int row0 = blockIdx.x * RB;
    const int lane8 = lane * 8;
    const int t0w   = 6 * w;

    // Biases for this lane's 8 units: j = 32w + q*16 + (lane>>4)*4 + r
    float bRv[2][4], bZv[2][4], bXNv[2][4], bHNv[2][4];
    #pragma unroll
    for (int q = 0; q < 2; ++q)
        #pragma unroll
        for (int r = 0; r < 4; ++r) {
            const int j = 32 * w + q * 16 + ((lane >> 4) << 2) + r;
            bRv[q][r]  = b_ih[j] + b_hh[j];
            bZv[q][r]  = b_ih[HH + j] + b_hh[HH + j];
            bXNv[q][r] = b_ih[2 * HH + j];
            bHNv[q][r] = b_hh[2 * HH + j];
        }

    float hprev[2][4];
    #pragma unroll
    for (int q = 0; q < 2; ++q)
        #pragma unroll
        for (int r = 0; r < 4; ++r) hprev[q][r] = 0.0f;

    // x mapping: row xn (0..15), 4 consecutive k at xk0
    const int xn = tid >> 5, xk0 = (tid & 31) * 4;
    const float* const xrow = x + (size_t)(row0 + xn) * TT * DD + xk0;
    const int xsec = 2 * (xk0 >> 5);
    const int xidx = (((xk0 & 31) >> 3) * 16 + xn) * 8 + (xk0 & 7);

    // ---- prime: x_0 fragments + zero h fragments of buf 0 ----
    {
        const float4 v = *(const float4*)xrow;
        const float vv[4] = {v.x, v.y, v.z, v.w};
        _Float16 xh[4], xl[4];
        #pragma unroll
        for (int u = 0; u < 4; ++u) {
            xh[u] = (_Float16)vv[u];
            xl[u] = (_Float16)((vv[u] - (float)xh[u]) * 2048.0f);
        }
        *(half4*)(FRAG(0, xsec) + xidx)     = half4{xh[0], xh[1], xh[2], xh[3]};
        *(half4*)(FRAG(0, xsec + 1) + xidx) = half4{xl[0], xl[1], xl[2], xl[3]};
        _Float16* hz = FRAG(0, 8);
        const half8 z8 = {};
        *(half8*)(hz + tid * 16)     = z8;
        *(half8*)(hz + tid * 16 + 8) = z8;
    }
    __syncthreads();

    const half8* __restrict__ WH = (const half8*)WF;

    for (int t = 0; t < TT; ++t) {
        const int cur = t & 1, nxtb = cur ^ 1;

        float4 pfx = make_float4(0.f, 0.f, 0.f, 0.f);
        const bool havepf = (t + 1 < TT);
        if (havepf) pfx = *(const float4*)(xrow + (size_t)(t + 1) * DD);

        // accs: aM/aX full-sum for r,z tiles and x-part for n tiles; aMh/aXh = n h-part
        f32x4 aM[6], aX[6], aMh[2], aXh[2];
        #pragma unroll
        for (int i = 0; i < 6; ++i) { aM[i] = f32x4{0.f,0.f,0.f,0.f}; aX[i] = f32x4{0.f,0.f,0.f,0.f}; }
        #pragma unroll
        for (int q = 0; q < 2; ++q) { aMh[q] = f32x4{0.f,0.f,0.f,0.f}; aXh[q] = f32x4{0.f,0.f,0.f,0.f}; }

        // ---- x-GEMM (k-steps 0..3): all tiles accumulate into aM/aX ----
        #pragma unroll 2
        for (int s = 0; s < 4; ++s) {
            const half8 bh = *(const half8*)(FRAG(cur, 2 * s) + lane8);
            const half8 bl = *(const half8*)(FRAG(cur, 2 * s + 1) + lane8);
            #pragma unroll
            for (int i = 0; i < 6; ++i) {
                const half8 wh = WH[((2 * s) * 48 + t0w + i) * 64 + lane];
                const half8 wl = WH[((2 * s + 1) * 48 + t0w + i) * 64 + lane];
                aM[i] = MFMA16(wh, bh, aM[i]);
                aX[i] = MFMA16(wh, bl, aX[i]);
                aX[i] = MFMA16(wl, bh, aX[i]);
            }
        }
        // ---- h-GEMM (k-steps 4..11): r,z tiles merge; n tiles go to aMh/aXh ----
        #pragma unroll 2
        for (int s = 4; s < 12; ++s) {
            const half8 bh = *(const half8*)(FRAG(cur, 2 * s) + lane8);
            const half8 bl = *(const half8*)(FRAG(cur, 2 * s + 1) + lane8);
            #pragma unroll
            for (int i = 0; i < 6; ++i) {
                const half8 wh = WH[((2 * s) * 48 + t0w + i) * 64 + lane];
                const half8 wl = WH[((2 * s + 1) * 48 + t0w + i) * 64 + lane];
                if (i % 3 == 2) {
                    const int q = i / 3;
                    aMh[q] = MFMA16(wh, bh, aMh[q]);
                    aXh[q] = MFMA16(wh, bl, aXh[q]);
                    aXh[q] = MFMA16(wl, bh, aXh[q]);
                } else {
                    aM[i] = MFMA16(wh, bh, aM[i]);
                    aX[i] = MFMA16(wh, bl, aX[i]);
                    aX[i] = MFMA16(wl, bh, aX[i]);
                }
            }
        }

        // ---- gates + h update, fully in-register ----
        #pragma unroll
        for (int q = 0; q < 2; ++q) {
            const int i0 = q * 3;
            _Float16 hh_[4], hl_[4];
            #pragma unroll
            for (int r = 0; r < 4; ++r) {
                const float sR  = aM[i0 + 0][r] + aX[i0 + 0][r] * INV2048 + bRv[q][r];
                const float sZ  = aM[i0 + 1][r] + aX[i0 + 1][r] * INV2048 + bZv[q][r];
                const float sXN = aM[i0 + 2][r] + aX[i0 + 2][r] * INV2048 + bXNv[q][r];
                const float sHN = aMh[q][r]     + aXh[q][r]     * INV2048 + bHNv[q][r];
                const float Rg = sigmoidf_(sR);
                const float Zg = sigmoidf_(sZ);
                const float Ng = tanhf(sXN + Rg * sHN);
                const float h = (1.0f - Zg) * Ng + Zg * hprev[q][r];
                hprev[q][r] = h;
                hh_[r] = (_Float16)h;
                hl_[r] = (_Float16)((h - (float)hh_[r]) * 2048.0f);
            }
            const int jb  = 32 * w + q * 16 + ((lane >> 4) << 2);
            const int sec = 2 * (4 + (jb >> 5));
            const int idx = (((jb & 31) >> 3) * 16 + (lane & 15)) * 8 + (jb & 7);
            *(half4*)(FRAG(nxtb, sec) + idx)     = half4{hh_[0], hh_[1], hh_[2], hh_[3]};
            *(half4*)(FRAG(nxtb, sec + 1) + idx) = half4{hl_[0], hl_[1], hl_[2], hl_[3]};
        }

        // ---- x_{t+1} fragments ----
        if (havepf) {
            const float vv[4] = {pfx.x, pfx.y, pfx.z, pfx.w};
            _Float16 xh[4], xl[4];
            #pragma unroll
            for (int u = 0; u < 4; ++u) {
                xh[u] = (_Float16)vv[u];
                xl[u] = (_Float16)((vv[u] - (float)xh[u]) * 2048.0f);
            }
            *(half4*)(FRAG(nxtb, xsec) + xidx)     = half4{xh[0], xh[1], xh[2], xh[3]};
            *(half4*)(FRAG(nxtb, xsec + 1) + xidx) = half4{xl[0], xl[1], xl[2], xl[3]};
        }
        __syncthreads();   // single barrier: frag[nxtb] complete; frag[cur] reads done
    }

    // ---- final h -> LDS fp32 ----
    #pragma unroll
    for (int q = 0; q < 2; ++q)
        #pragma unroll
        for (int r = 0; r < 4; ++r) {
            const int j = 32 * w + q * 16 + ((lane >> 4) << 2) + r;
            hsF[j * RB + (lane & 15)] = hprev[q][r];
        }
    __syncthreads();

    // ---- cdist^2 + argmin: thread covers protos {tid, +512, +1024, +1536} ----
    float bv[16]; int bi[16];
    #pragma unroll
    for (int r = 0; r < 16; ++r) { bv[r] = 3.4e38f; bi[r] = 0; }
    for (int m = 0; m < 4; ++m) {
        const int p = m * 512 + tid;
        float d2[16];
        #pragma unroll
        for (int r = 0; r < 16; ++r) d2[r] = 0.f;
        #pragma unroll 2
        for (int k = 0; k < HH; ++k) {
            const float pv = pT[(size_t)k * PP + p];
            #pragma unroll
            for (int g4 = 0; g4 < 4; ++g4) {
                const float4 hv = *(const float4*)&hsF[k * RB + g4 * 4];
                float d;
                d = hv.x - pv; d2[g4 * 4 + 0] += d * d;
                d = hv.y - pv; d2[g4 * 4 + 1] += d * d;
                d = hv.z - pv; d2[g4 * 4 + 2] += d * d;
                d = hv.w - pv; d2[g4 * 4 + 3] += d * d;
            }
        }
        #pragma unroll
        for (int r = 0; r < 16; ++r)
            if (d2[r] < bv[r]) { bv[r] = d2[r]; bi[r] = p; }  // ascending p: lowest on tie
    }
    #pragma unroll
    for (int s = 1; s < 64; s <<= 1) {
        #pragma unroll
        for (int r = 0; r < 16; ++r) {
            const float ov = __shfl_xor(bv[r], s);
            const int   oi = __shfl_xor(bi[r], s);
            if (ov < bv[r] || (ov == bv[r] && oi < bi[r])) { bv[r] = ov; bi[r] = oi; }
        }
    }
    if (lane == 0) {
        #pragma unroll
        for (int r = 0; r < 16; ++r) { redv[w][r] = bv[r]; redi[w][r] = bi[r]; }
    }
    __syncthreads();
    if (tid < RB) {
        float v = redv[0][tid]; int idx = redi[0][tid];
        #pragma unroll
        for (int u = 1; u < 8; ++u) {
            const float ov = redv[u][tid]; const int oi = redi[u][tid];
            if (ov < v || (ov == v && oi < idx)) { v = ov; idx = oi; }
        }
        out[row0 + tid] = idx;
    }
}

extern "C" void kernel_launch(void* const* d_in, const int* in_sizes, int n_in,
                              void* d_out, int out_size, void* d_ws, size_t ws_size,
                              hipStream_t stream) {
    const float* x      = (const float*)d_in[0];
    const float* w_ih   = (const float*)d_in[1];
    const float* w_hh   = (const float*)d_in[2];
    const float* b_ih   = (const float*)d_in[3];
    const float* b_hh   = (const float*)d_in[4];
    const float* protos = (const float*)d_in[5];
    int* out = (int*)d_out;

    _Float16* WF = (_Float16*)d_ws;                                   // 1.125 MB
    float*    pT = (float*)((char*)d_ws + 589824 * sizeof(_Float16)); // 2 MB

    hipLaunchKernelGGL(prep_kernel, dim3((HH * PP + 255) / 256), dim3(256), 0, stream,
                       w_ih, w_hh, protos, WF, pT);
    hipLaunchKernelGGL(gru_kernel, dim3(NBLK), dim3(NTH), 0, stream,
                       x, WF, b_ih, b_hh, pT, out);
}

// Round 10
// 2952.187 us; speedup vs baseline: 3.7144x; 1.2652x over previous
//
#include <hip/hip_runtime.h>

// Problem constants
#define TT 256
#define DD 128
#define HH 256
#define PP 2048
#define RB 16     // rows per block
#define NBLK 128  // 2048/16
#define NTH 1024  // 16 waves, 4 per SIMD

typedef _Float16 half8 __attribute__((ext_vector_type(8)));
typedef _Float16 half4 __attribute__((ext_vector_type(4)));
typedef float f32x4 __attribute__((ext_vector_type(4)));

#define MFMA16(a, b, c) __builtin_amdgcn_mfma_f32_16x16x32_f16((a), (b), (c), 0, 0, 0)
#define INV2048 (4.8828125e-4f)

__device__ __forceinline__ float sigmoidf_(float v) { return 1.0f / (1.0f + expf(-v)); }

// ---------------------------------------------------------------------------
// Weight fragments (UNCHANGED layout from rounds 6-9 — verified absmax 0):
// sections sec = 2*s+part (s: 0..3 x-k, 4..11 h-k; part 0 hi, 1 lo*2048),
// each section = 48 tiles x 512 halves. Tile tt = chunk*3 + gate covers
// gate-type (tt%3) of units (tt/3)*16..+15; element (m,k): half
// (m + 16*(k>>3))*8 + (k&7).
__global__ void prep_kernel(const float* __restrict__ w_ih, const float* __restrict__ w_hh,
                            const float* __restrict__ protos,
                            _Float16* __restrict__ WF, float* __restrict__ pT) {
    int f = blockIdx.x * blockDim.x + threadIdx.x;
    if (f < 294912) {
        int s = f / 24576, rem = f % 24576;
        int tt = rem / 512, rem2 = rem % 512;
        int m = rem2 >> 5, kl = rem2 & 31;
        int grow = (tt % 3) * 256 + (tt / 3) * 16 + m;
        float v = (s < 4) ? w_ih[grow * DD + s * 32 + kl]
                          : w_hh[grow * HH + (s - 4) * 32 + kl];
        _Float16 hi = (_Float16)v;
        _Float16 lo = (_Float16)((v - (float)hi) * 2048.0f);
        int lane = m + 16 * (kl >> 3);
        int base = ((s * 2 + 0) * 48 + tt) * 512 + lane * 8 + (kl & 7);
        WF[base] = hi;
        WF[base + 48 * 512] = lo;
    }
    if (f < HH * PP) pT[f] = protos[(f & (PP - 1)) * HH + (f >> 11)];
}

// ---------------------------------------------------------------------------
// 16 waves; wave w owns tiles 3w..3w+2 = chunk w x gates {r,z,n}.
// Lane's C-fragments across the 3 tiles refer to the SAME (4 units, 1 row)
// -> gates fully in-register, 1 barrier/step. 4 waves/SIMD hide L2 latency.
__launch_bounds__(NTH)
__global__ void gru_kernel(const float* __restrict__ x,
                           const _Float16* __restrict__ WF,
                           const float* __restrict__ b_ih, const float* __restrict__ b_hh,
                           const float* __restrict__ pT,
                           int* __restrict__ out) {
    __shared__ __align__(16) _Float16 fragB[2 * 24 * 512];  // 48 KB activation fragments
    __shared__ float hsF[HH * RB];                          // 16 KB final h
    __shared__ float redv[16][RB];
    __shared__ int   redi[16][RB];
#define FRAG(b, sec) (fragB + ((b) * 24 + (sec)) * 512)

    const int tid  = threadIdx.x;
    const int lane = tid & 63;
    const int w    = tid >> 6;          // 0..15: chunk id
    const int row0 = blockIdx.x * RB;
    const int lane8 = lane * 8;
    const int t0w   = 3 * w;

    // Biases for this lane's 4 units: j = 16w + (lane>>4)*4 + r
    float bRv[4], bZv[4], bXNv[4], bHNv[4];
    #pragma unroll
    for (int r = 0; r < 4; ++r) {
        const int j = 16 * w + ((lane >> 4) << 2) + r;
        bRv[r]  = b_ih[j] + b_hh[j];
        bZv[r]  = b_ih[HH + j] + b_hh[HH + j];
        bXNv[r] = b_ih[2 * HH + j];
        bHNv[r] = b_hh[2 * HH + j];
    }

    float hprev[4] = {0.f, 0.f, 0.f, 0.f};

    // x mapping (tid<512): row xn (0..15), 4 consecutive k at xk0
    const int xn = tid >> 5, xk0 = (tid & 31) * 4;
    const float* const xrow = x + (size_t)(row0 + (xn & 15)) * TT * DD + xk0;
    const int xsec = 2 * (xk0 >> 5);
    const int xidx = (((xk0 & 31) >> 3) * 16 + (xn & 15)) * 8 + (xk0 & 7);

    // ---- prime: x_0 fragments + zero h fragments of buf 0 ----
    if (tid < 512) {
        const float4 v = *(const float4*)xrow;
        const float vv[4] = {v.x, v.y, v.z, v.w};
        _Float16 xh[4], xl[4];
        #pragma unroll
        for (int u = 0; u < 4; ++u) {
            xh[u] = (_Float16)vv[u];
            xl[u] = (_Float16)((vv[u] - (float)xh[u]) * 2048.0f);
        }
        *(half4*)(FRAG(0, xsec) + xidx)     = half4{xh[0], xh[1], xh[2], xh[3]};
        *(half4*)(FRAG(0, xsec + 1) + xidx) = half4{xl[0], xl[1], xl[2], xl[3]};
        _Float16* hz = FRAG(0, 8);
        const half8 z8 = {};
        *(half8*)(hz + tid * 16)     = z8;
        *(half8*)(hz + tid * 16 + 8) = z8;
    }
    __syncthreads();

    const half8* __restrict__ WH = (const half8*)WF;

    for (int t = 0; t < TT; ++t) {
        const int cur = t & 1, nxtb = cur ^ 1;

        float4 pfx = make_float4(0.f, 0.f, 0.f, 0.f);
        const bool havepf = (t + 1 < TT) && (tid < 512);
        if (havepf) pfx = *(const float4*)(xrow + (size_t)(t + 1) * DD);

        // accs: aM/aX = {r, z, n-x-part}; aMh/aXh = n h-part
        f32x4 aM[3], aX[3], aMh, aXh;
        #pragma unroll
        for (int i = 0; i < 3; ++i) { aM[i] = f32x4{0.f,0.f,0.f,0.f}; aX[i] = f32x4{0.f,0.f,0.f,0.f}; }
        aMh = f32x4{0.f,0.f,0.f,0.f}; aXh = f32x4{0.f,0.f,0.f,0.f};

        // ---- x-GEMM (k-steps 0..3): all 3 tiles accumulate into aM/aX ----
        #pragma unroll 2
        for (int s = 0; s < 4; ++s) {
            const half8 bh = *(const half8*)(FRAG(cur, 2 * s) + lane8);
            const half8 bl = *(const half8*)(FRAG(cur, 2 * s + 1) + lane8);
            #pragma unroll
            for (int i = 0; i < 3; ++i) {
                const half8 wh = WH[((2 * s) * 48 + t0w + i) * 64 + lane];
                const half8 wl = WH[((2 * s + 1) * 48 + t0w + i) * 64 + lane];
                aM[i] = MFMA16(wh, bh, aM[i]);
                aX[i] = MFMA16(wh, bl, aX[i]);
                aX[i] = MFMA16(wl, bh, aX[i]);
            }
        }
        // ---- h-GEMM (k-steps 4..11): r,z merge; n goes to aMh/aXh ----
        #pragma unroll 2
        for (int s = 4; s < 12; ++s) {
            const half8 bh = *(const half8*)(FRAG(cur, 2 * s) + lane8);
            const half8 bl = *(const half8*)(FRAG(cur, 2 * s + 1) + lane8);
            #pragma unroll
            for (int i = 0; i < 3; ++i) {
                const half8 wh = WH[((2 * s) * 48 + t0w + i) * 64 + lane];
                const half8 wl = WH[((2 * s + 1) * 48 + t0w + i) * 64 + lane];
                if (i == 2) {
                    aMh = MFMA16(wh, bh, aMh);
                    aXh = MFMA16(wh, bl, aXh);
                    aXh = MFMA16(wl, bh, aXh);
                } else {
                    aM[i] = MFMA16(wh, bh, aM[i]);
                    aX[i] = MFMA16(wh, bl, aX[i]);
                    aX[i] = MFMA16(wl, bh, aX[i]);
                }
            }
        }

        // ---- gates + h update, fully in-register ----
        {
            _Float16 hh_[4], hl_[4];
            #pragma unroll
            for (int r = 0; r < 4; ++r) {
                const float sR  = aM[0][r] + aX[0][r] * INV2048 + bRv[r];
                const float sZ  = aM[1][r] + aX[1][r] * INV2048 + bZv[r];
                const float sXN = aM[2][r] + aX[2][r] * INV2048 + bXNv[r];
                const float sHN = aMh[r]   + aXh[r]   * INV2048 + bHNv[r];
                const float Rg = sigmoidf_(sR);
                const float Zg = sigmoidf_(sZ);
                const float Ng = tanhf(sXN + Rg * sHN);
                const float h = (1.0f - Zg) * Ng + Zg * hprev[r];
                hprev[r] = h;
                hh_[r] = (_Float16)h;
                hl_[r] = (_Float16)((h - (float)hh_[r]) * 2048.0f);
            }
            const int jb  = 16 * w + ((lane >> 4) << 2);
            const int sec = 2 * (4 + (jb >> 5));
            const int idx = (((jb & 31) >> 3) * 16 + (lane & 15)) * 8 + (jb & 7);
            *(half4*)(FRAG(nxtb, sec) + idx)     = half4{hh_[0], hh_[1], hh_[2], hh_[3]};
            *(half4*)(FRAG(nxtb, sec + 1) + idx) = half4{hl_[0], hl_[1], hl_[2], hl_[3]};
        }

        // ---- x_{t+1} fragments ----
        if (havepf) {
            const float vv[4] = {pfx.x, pfx.y, pfx.z, pfx.w};
            _Float16 xh[4], xl[4];
            #pragma unroll
            for (int u = 0; u < 4; ++u) {
                xh[u] = (_Float16)vv[u];
                xl[u] = (_Float16)((vv[u] - (float)xh[u]) * 2048.0f);
            }
            *(half4*)(FRAG(nxtb, xsec) + xidx)     = half4{xh[0], xh[1], xh[2], xh[3]};
            *(half4*)(FRAG(nxtb, xsec + 1) + xidx) = half4{xl[0], xl[1], xl[2], xl[3]};
        }
        __syncthreads();   // single barrier: frag[nxtb] complete; frag[cur] reads done
    }

    // ---- final h -> LDS fp32 ----
    #pragma unroll
    for (int r = 0; r < 4; ++r) {
        const int j = 16 * w + ((lane >> 4) << 2) + r;
        hsF[j * RB + (lane & 15)] = hprev[r];
    }
    __syncthreads();

    // ---- cdist^2 + argmin: thread covers protos {tid, tid+1024} ----
    float bv[16]; int bi[16];
    #pragma unroll
    for (int r = 0; r < 16; ++r) { bv[r] = 3.4e38f; bi[r] = 0; }
    for (int m = 0; m < 2; ++m) {
        const int p = m * 1024 + tid;
        float d2[16];
        #pragma unroll
        for (int r = 0; r < 16; ++r) d2[r] = 0.f;
        #pragma unroll 2
        for (int k = 0; k < HH; ++k) {
            const float pv = pT[(size_t)k * PP + p];
            #pragma unroll
            for (int g4 = 0; g4 < 4; ++g4) {
                const float4 hv = *(const float4*)&hsF[k * RB + g4 * 4];
                float d;
                d = hv.x - pv; d2[g4 * 4 + 0] += d * d;
                d = hv.y - pv; d2[g4 * 4 + 1] += d * d;
                d = hv.z - pv; d2[g4 * 4 + 2] += d * d;
                d = hv.w - pv; d2[g4 * 4 + 3] += d * d;
            }
        }
        #pragma unroll
        for (int r = 0; r < 16; ++r)
            if (d2[r] < bv[r]) { bv[r] = d2[r]; bi[r] = p; }  // ascending p: lowest on tie
    }
    #pragma unroll
    for (int s = 1; s < 64; s <<= 1) {
        #pragma unroll
        for (int r = 0; r < 16; ++r) {
            const float ov = __shfl_xor(bv[r], s);
            const int   oi = __shfl_xor(bi[r], s);
            if (ov < bv[r] || (ov == bv[r] && oi < bi[r])) { bv[r] = ov; bi[r] = oi; }
        }
    }
    if (lane == 0) {
        #pragma unroll
        for (int r = 0; r < 16; ++r) { redv[w][r] = bv[r]; redi[w][r] = bi[r]; }
    }
    __syncthreads();
    if (tid < RB) {
        float v = redv[0][tid]; int idx = redi[0][tid];
        #pragma unroll
        for (int u = 1; u < 16; ++u) {
            const float ov = redv[u][tid]; const int oi = redi[u][tid];
            if (ov < v || (ov == v && oi < idx)) { v = ov; idx = oi; }
        }
        out[row0 + tid] = idx;
    }
}

extern "C" void kernel_launch(void* const* d_in, const int* in_sizes, int n_in,
                              void* d_out, int out_size, void* d_ws, size_t ws_size,
                              hipStream_t stream) {
    const float* x      = (const float*)d_in[0];
    const float* w_ih   = (const float*)d_in[1];
    const float* w_hh   = (const float*)d_in[2];
    const float* b_ih   = (const float*)d_in[3];
    const float* b_hh   = (const float*)d_in[4];
    const float* protos = (const float*)d_in[5];
    int* out = (int*)d_out;

    _Float16* WF = (_Float16*)d_ws;                                   // 1.125 MB
    float*    pT = (float*)((char*)d_ws + 589824 * sizeof(_Float16)); // 2 MB

    hipLaunchKernelGGL(prep_kernel, dim3((HH * PP + 255) / 256), dim3(256), 0, stream,
                       w_ih, w_hh, protos, WF, pT);
    hipLaunchKernelGGL(gru_kernel, dim3(NBLK), dim3(NTH), 0, stream,
                       x, WF, b_ih, b_hh, pT, out);
}